// Round 10
// baseline (930.701 us; speedup 1.0000x reference)
//
#include <hip/hip_runtime.h>
#include <hip/hip_bf16.h>

#define BATCH 32
#define NN 1024
#define MM 1024
#define KK 64
#define DD 2052                         // padded diag rows (used up to 2048)
#define SCALE 14.4269504088896f         // 1/(gamma*ln2), gamma = 0.1
#define INV_SCALE 0.0693147180559945f   // gamma*ln2
#define BIGU 1.44269504e11f             // 1e10 * SCALE

typedef _Float16 h4 __attribute__((ext_vector_type(4)));
typedef float f4 __attribute__((ext_vector_type(4)));

// Fused: LDS-write visibility + barrier in ONE asm (no compiler reordering
// around it, no vmcnt drain -> D prefetch loads stay in flight).
#define LDS_BARRIER() asm volatile("s_waitcnt lgkmcnt(0)\ns_barrier" ::: "memory")

// ---------------------------------------------------------------------------
// Kernel 1: pairwise sq-Euclidean distances, pre-scaled by 1/(gamma*ln2),
// stored f16. Unchanged from the verified R5/R7/R9 version.
// ---------------------------------------------------------------------------
template <int DIAG>
__global__ __launch_bounds__(256) void dist_kernel(
    const float* __restrict__ x, const float* __restrict__ y,
    _Float16* __restrict__ D) {
  const int b  = blockIdx.z;
  const int ti = blockIdx.y;
  const int tj = blockIdx.x;
  const int t  = threadIdx.x;

  __shared__ float xs[64][68];
  __shared__ float ys[64][68];

  {
    const int lr = t >> 4;
    const int lc = (t & 15) * 4;
    const float* xp = x + (size_t)(b * NN + ti * 64) * KK;
    const float* yp = y + (size_t)(b * MM + tj * 64) * KK;
#pragma unroll
    for (int r = 0; r < 4; ++r) {
      const int row = lr + r * 16;
      f4 xv = *(const f4*)(xp + (size_t)row * KK + lc);
      f4 yv = *(const f4*)(yp + (size_t)row * KK + lc);
      xs[row][lc + 0] = xv[0]; xs[row][lc + 1] = xv[1];
      xs[row][lc + 2] = xv[2]; xs[row][lc + 3] = xv[3];
      ys[row][lc + 0] = yv[0]; ys[row][lc + 1] = yv[1];
      ys[row][lc + 2] = yv[2]; ys[row][lc + 3] = yv[3];
    }
  }
  __syncthreads();

  const int tx = (t & 15) * 4;
  const int ty = (t >> 4) * 4;

  float acc[4][4];
  float x2[4], y2[4];
#pragma unroll
  for (int a = 0; a < 4; ++a) {
    x2[a] = 0.f; y2[a] = 0.f;
#pragma unroll
    for (int c = 0; c < 4; ++c) acc[a][c] = 0.f;
  }

#pragma unroll 4
  for (int k = 0; k < KK; k += 4) {
    f4 xa[4], yb[4];
#pragma unroll
    for (int a = 0; a < 4; ++a) xa[a] = *(const f4*)&xs[ty + a][k];
#pragma unroll
    for (int c = 0; c < 4; ++c) yb[c] = *(const f4*)&ys[tx + c][k];
#pragma unroll
    for (int a = 0; a < 4; ++a) {
      x2[a] += xa[a][0] * xa[a][0] + xa[a][1] * xa[a][1] +
               xa[a][2] * xa[a][2] + xa[a][3] * xa[a][3];
      y2[a] += yb[a][0] * yb[a][0] + yb[a][1] * yb[a][1] +
               yb[a][2] * yb[a][2] + yb[a][3] * yb[a][3];
    }
#pragma unroll
    for (int a = 0; a < 4; ++a)
#pragma unroll
      for (int c = 0; c < 4; ++c)
        acc[a][c] += xa[a][0] * yb[c][0] + xa[a][1] * yb[c][1] +
                     xa[a][2] * yb[c][2] + xa[a][3] * yb[c][3];
  }

  if constexpr (DIAG) {
    __shared__ _Float16 dbuf[127][66];
#pragma unroll
    for (int a = 0; a < 4; ++a)
#pragma unroll
      for (int c = 0; c < 4; ++c) {
        const int li = ty + a, lj = tx + c;
        dbuf[li + lj][li] =
            (_Float16)((x2[a] + y2[c] - 2.0f * acc[a][c]) * SCALE);
      }
    __syncthreads();

    _Float16* Db = D + (size_t)b * DD * NN;
    const int wave = t >> 6, lane = t & 63;
    const int d0 = ti * 64 + tj * 64;
    const int c0 = ti * 64;
    for (int ld = wave; ld < 127; ld += 4) {
      const int lo = ld > 63 ? ld - 63 : 0;
      const int hi = ld < 63 ? ld : 63;
      const int li = lo + lane;
      if (li <= hi)
        Db[(size_t)(d0 + ld) * NN + c0 + li] = dbuf[ld][li];
    }
  } else {
    _Float16* Dp = D + (size_t)b * NN * MM + (size_t)(ti * 64 + ty) * MM +
                   (tj * 64 + tx);
#pragma unroll
    for (int a = 0; a < 4; ++a) {
      h4 v;
#pragma unroll
      for (int c = 0; c < 4; ++c)
        v[c] = (_Float16)((x2[a] + y2[c] - 2.0f * acc[a][c]) * SCALE);
      *(h4*)(Dp + (size_t)a * MM) = v;
    }
  }
}

// ---------------------------------------------------------------------------
// Kernel 2 (diag layout), halo version: 4 diagonals per barrier.
// Thread t owns rows i0..i0+3 (i0=4t); state w1/w2[8] covers rows i0-4..i0+3.
// R10 change vs R9: exchange buffer is SoA — lex[parity][q][thread] — so each
// ds_write_b32/ds_read_b32 has lane t on bank t%32 (2 lanes/bank = free).
// R9's AoS lsx[2][256][8] put every lane's f4 on banks 0-3 (64-way conflict,
// 1.57M conflict cycles = the entire round cost).
// ---------------------------------------------------------------------------
__global__ __launch_bounds__(256) void dtw_diag_kernel(
    const _Float16* __restrict__ Dd, float* __restrict__ out) {
  const int b  = blockIdx.x;
  const int t  = threadIdx.x;
  const int i0 = t * 4;
  const _Float16* Db = Dd + (size_t)b * DD * NN;

  __shared__ float lex[2][8][256];   // [parity][slot: w1[4..7],w2[4..7]][thread]

  float w1[8], w2[8];
#pragma unroll
  for (int j = 0; j < 8; ++j) { w1[j] = BIGU; w2[j] = BIGU; }
  if (t == 0) w1[4] = (float)Db[0];   // R[0,0] = D[0,0] (diag 0, row 0)

  // D banks: lo covers rows i0-4..i0-1, hi covers i0..i0+3, per diag c=0..3.
  h4 Al0, Al1, Al2, Ah0, Ah1, Ah2, Ah3;
  h4 Bl0, Bl1, Bl2, Bh0, Bh1, Bh2, Bh3;

#define STAGE(L0, L1, L2, H0, H1, H2, H3, D0S)                                \
  do {                                                                        \
    const long long _o = (long long)(D0S)*NN;                                 \
    L0 = *(const h4*)(Db + (size_t)(_o + i0 - 4));                            \
    L1 = *(const h4*)(Db + (size_t)(_o + NN + i0 - 4));                       \
    L2 = *(const h4*)(Db + (size_t)(_o + 2 * NN + i0 - 4));                   \
    H0 = *(const h4*)(Db + (size_t)(_o + i0));                                \
    H1 = *(const h4*)(Db + (size_t)(_o + NN + i0));                           \
    H2 = *(const h4*)(Db + (size_t)(_o + 2 * NN + i0));                       \
    H3 = *(const h4*)(Db + (size_t)(_o + 3 * NN + i0));                       \
  } while (0)

#define EXCHANGE(PAR)                                                         \
  do {                                                                        \
    lex[PAR][0][t] = w1[4]; lex[PAR][1][t] = w1[5];                           \
    lex[PAR][2][t] = w1[6]; lex[PAR][3][t] = w1[7];                           \
    lex[PAR][4][t] = w2[4]; lex[PAR][5][t] = w2[5];                           \
    lex[PAR][6][t] = w2[6]; lex[PAR][7][t] = w2[7];                           \
    LDS_BARRIER();                                                            \
    if (t > 0) {                                                              \
      w1[0] = lex[PAR][0][t - 1]; w1[1] = lex[PAR][1][t - 1];                 \
      w1[2] = lex[PAR][2][t - 1]; w1[3] = lex[PAR][3][t - 1];                 \
      w2[0] = lex[PAR][4][t - 1]; w2[1] = lex[PAR][5][t - 1];                 \
      w2[2] = lex[PAR][6][t - 1]; w2[3] = lex[PAR][7][t - 1];                 \
    }                                                                         \
  } while (0)

  // One DP cell, in-place (descending j keeps j-1 values old).
#define CELL(J, DV, DG)                                                       \
  do {                                                                        \
    const int _ri = i0 - 4 + (J);                                             \
    const bool _v =                                                           \
        ((unsigned)_ri < (unsigned)NN) && ((unsigned)((DG)-_ri) < (unsigned)MM); \
    const float _a = w2[(J)-1], _b = w1[(J)-1], _c = w1[(J)];                 \
    const float _mn = fminf(fminf(_a, _b), _c);                               \
    const float _md = __builtin_amdgcn_fmed3f(_a, _b, _c);                    \
    const float _mx = fmaxf(fmaxf(_a, _b), _c);                               \
    const float _s = 1.0f + __builtin_amdgcn_exp2f(_mn - _md) +               \
                     __builtin_amdgcn_exp2f(_mn - _mx);                       \
    w2[(J)] = w1[(J)];                                                        \
    w1[(J)] = _v ? (float)(DV) + _mn - __builtin_amdgcn_logf(_s) : BIGU;      \
  } while (0)

#define BLOCK4(PAR, L0, L1, L2, H0, H1, H2, H3, D0V)                          \
  do {                                                                        \
    EXCHANGE(PAR);                                                            \
    const int _d = (D0V);                                                     \
    /* c=1, diag _d,   j=7..1 */                                              \
    CELL(7, H0[3], _d); CELL(6, H0[2], _d); CELL(5, H0[1], _d);               \
    CELL(4, H0[0], _d); CELL(3, L0[3], _d); CELL(2, L0[2], _d);               \
    CELL(1, L0[1], _d);                                                       \
    /* c=2, diag _d+1, j=7..2 */                                              \
    CELL(7, H1[3], _d + 1); CELL(6, H1[2], _d + 1); CELL(5, H1[1], _d + 1);   \
    CELL(4, H1[0], _d + 1); CELL(3, L1[3], _d + 1); CELL(2, L1[2], _d + 1);   \
    /* c=3, diag _d+2, j=7..3 */                                              \
    CELL(7, H2[3], _d + 2); CELL(6, H2[2], _d + 2); CELL(5, H2[1], _d + 2);   \
    CELL(4, H2[0], _d + 2); CELL(3, L2[3], _d + 2);                           \
    /* c=4, diag _d+3, j=7..4 */                                              \
    CELL(7, H3[3], _d + 3); CELL(6, H3[2], _d + 3); CELL(5, H3[1], _d + 3);   \
    CELL(4, H3[0], _d + 3);                                                   \
  } while (0)

  STAGE(Al0, Al1, Al2, Ah0, Ah1, Ah2, Ah3, 1);   // block 0: diags 1..4
  STAGE(Bl0, Bl1, Bl2, Bh0, Bh1, Bh2, Bh3, 5);   // block 1: diags 5..8

  int d0 = 1;
  for (int n = 0; n < 255; ++n) {   // 255 pairs = blocks 0..509, diags 1..2040
    BLOCK4(0, Al0, Al1, Al2, Ah0, Ah1, Ah2, Ah3, d0);
    STAGE(Al0, Al1, Al2, Ah0, Ah1, Ah2, Ah3, d0 + 8);
    BLOCK4(1, Bl0, Bl1, Bl2, Bh0, Bh1, Bh2, Bh3, d0 + 4);
    STAGE(Bl0, Bl1, Bl2, Bh0, Bh1, Bh2, Bh3, d0 + 12);
    d0 += 8;
  }
  // d0 == 2041 here. Block 510 (parity 0, bank A): diags 2041..2044.
  BLOCK4(0, Al0, Al1, Al2, Ah0, Ah1, Ah2, Ah3, 2041);

  // Peel (parity 1, bank B staged with D0S=2045): diags 2045, 2046.
  EXCHANGE(1);
  CELL(7, Bh0[3], 2045); CELL(6, Bh0[2], 2045); CELL(5, Bh0[1], 2045);
  CELL(4, Bh0[0], 2045); CELL(3, Bl0[3], 2045); CELL(2, Bl0[2], 2045);
  CELL(1, Bl0[1], 2045);
  CELL(7, Bh1[3], 2046); CELL(6, Bh1[2], 2046); CELL(5, Bh1[1], 2046);
  CELL(4, Bh1[0], 2046); CELL(3, Bl1[3], 2046); CELL(2, Bl1[2], 2046);

  if (t == 255) out[b] = w1[7] * INV_SCALE;   // R[1023,1023], diag 2046

#undef STAGE
#undef EXCHANGE
#undef CELL
#undef BLOCK4
}

// ---------------------------------------------------------------------------
// Kernel 2 (row-major fallback): unchanged verified version.
// ---------------------------------------------------------------------------
__global__ __launch_bounds__(256) void dtw_row_kernel(
    const _Float16* __restrict__ D, float* __restrict__ out) {
  const int b  = blockIdx.x;
  const int t  = threadIdx.x;
  const int i0 = t * 4;
  const _Float16* Dr = D + (size_t)(b * NN + i0) * MM;

  __shared__ float lx[2][256];

  float r1[4], r2[4];
#pragma unroll
  for (int k = 0; k < 4; ++k) { r1[k] = BIGU; r2[k] = BIGU; }
  if (t == 0) r1[0] = (float)Dr[0];

  float dv[4], dvn[4];
#pragma unroll
  for (int k = 0; k < 4; ++k) {
    int j1 = 1 - (i0 + k);
    int jc1 = j1 < 0 ? 0 : (j1 > MM - 1 ? MM - 1 : j1);
    dv[k] = (float)Dr[(size_t)k * MM + jc1];
    int j2 = 2 - (i0 + k);
    int jc2 = j2 < 0 ? 0 : (j2 > MM - 1 ? MM - 1 : j2);
    dvn[k] = (float)Dr[(size_t)k * MM + jc2];
  }

  float nl1_prev = BIGU;

  for (int d = 1; d <= NN + MM - 2; ++d) {
    const int pp = d & 1;
    lx[pp][t] = r1[3];
    __syncthreads();
    const float nl1 = (t > 0) ? lx[pp][t - 1] : BIGU;
    const float nl2 = nl1_prev;

    float rn[4];
#pragma unroll
    for (int k = 0; k < 4; ++k) {
      const int j = d - (i0 + k);
      const float a  = k ? r2[k - 1] : nl2;
      const float bb = k ? r1[k - 1] : nl1;
      const float c  = r1[k];
      const float m  = fminf(fminf(a, bb), c);
      const float s  = exp2f(m - a) + exp2f(m - bb) + exp2f(m - c);
      const float sm = m - log2f(s);
      rn[k] = (j >= 0 && j < MM) ? dv[k] + sm : BIGU;
    }

    nl1_prev = nl1;
#pragma unroll
    for (int k = 0; k < 4; ++k) { r2[k] = r1[k]; r1[k] = rn[k]; dv[k] = dvn[k]; }

    const int dn = d + 2;
#pragma unroll
    for (int k = 0; k < 4; ++k) {
      int j = dn - (i0 + k);
      int jc = j < 0 ? 0 : (j > MM - 1 ? MM - 1 : j);
      dvn[k] = (float)Dr[(size_t)k * MM + jc];
    }
  }

  if (t == 255) out[b] = r1[3] * INV_SCALE;
}

// ---------------------------------------------------------------------------
extern "C" void kernel_launch(void* const* d_in, const int* in_sizes, int n_in,
                              void* d_out, int out_size, void* d_ws,
                              size_t ws_size, hipStream_t stream) {
  const float* x = (const float*)d_in[0];
  const float* y = (const float*)d_in[1];
  float* out = (float*)d_out;

  const size_t need_diag = (size_t)BATCH * DD * NN * sizeof(_Float16);  // ~134.5 MiB
  const size_t need_row  = (size_t)BATCH * NN * MM * sizeof(_Float16);  //   64  MiB
  dim3 g1(MM / 64, NN / 64, BATCH);

  if (ws_size >= need_diag) {
    _Float16* Dd = (_Float16*)d_ws;
    dist_kernel<1><<<g1, 256, 0, stream>>>(x, y, Dd);
    dtw_diag_kernel<<<BATCH, 256, 0, stream>>>(Dd, out);
  } else if (ws_size >= need_row) {
    _Float16* D = (_Float16*)d_ws;
    dist_kernel<0><<<g1, 256, 0, stream>>>(x, y, D);
    dtw_row_kernel<<<BATCH, 256, 0, stream>>>(D, out);
  }
  // else: workspace too small — fail visibly (output stays zero)
}